// Round 13
// baseline (99.545 us; speedup 1.0000x reference)
//
#include <hip/hip_runtime.h>
#include <hip/hip_fp16.h>

typedef __attribute__((ext_vector_type(8))) _Float16 half8;
typedef __attribute__((ext_vector_type(4))) float f32x4;

// DPP rotate-reduce within each 16-lane row: after ror 1,2,4,8 all 16 lanes
// hold the group sum. Validated numerically R6-R12.
template <int CTRL>
__device__ __forceinline__ float dpp_ror_add(float p) {
  int s = __builtin_amdgcn_update_dpp(0, __float_as_int(p), CTRL, 0xF, 0xF, true);
  return p + __int_as_float(s);
}

__device__ __forceinline__ unsigned int pack_f16x2(float a, float b) {
  __half2 h = __floats2half2_rn(a, b);  // .x (low) = a
  return *reinterpret_cast<unsigned int*>(&h);
}

// relu on 8 packed f16 via guaranteed v_pk_max_f16 (validated R9-R12).
__device__ __forceinline__ half8 relu8(half8 v) {
  union { half8 h8; unsigned int u[4]; } a;
  a.h8 = v;
  unsigned int z = 0;
#pragma unroll
  for (int e = 0; e < 4; ++e)
    asm("v_pk_max_f16 %0, %1, %2" : "=v"(a.u[e]) : "v"(a.u[e]), "v"(z));
  return a.h8;
}

// ---------------------------------------------------------------------------
// Precompute (fp32 math, f16 outputs, packed as uint pairs):
//   hx2[512][128] uint = f16 pairs of x @ W1[:128]
//   hy2[512][128] uint = f16 pairs of y @ W1[128:] + b1
//   W2T2[n][128]  uint = f16 pairs of W2[k][n] (transposed)
// ---------------------------------------------------------------------------
__global__ void k_pre(const float* __restrict__ x, const float* __restrict__ y,
                      const float* __restrict__ W1, const float* __restrict__ b1,
                      const float* __restrict__ W2,
                      unsigned int* __restrict__ hx2, unsigned int* __restrict__ hy2,
                      unsigned int* __restrict__ W2T2) {
  const int b = blockIdx.x;
  const int t = threadIdx.x;
  if (b < 128) {
    const bool isx = (b < 64);
    const int i0 = (isx ? b : (b - 64)) * 8;
    const float* __restrict__ src = isx ? x : y;
    const float* __restrict__ W = W1 + (isx ? 0 : 128 * 256);
    float acc[8];
    const float binit = isx ? 0.0f : b1[t];
#pragma unroll
    for (int r = 0; r < 8; ++r) acc[r] = binit;
#pragma unroll 4
    for (int d = 0; d < 128; ++d) {
      const float wv = W[d * 256 + t];  // coalesced across t
#pragma unroll
      for (int r = 0; r < 8; ++r) acc[r] += src[(i0 + r) * 128 + d] * wv;  // uniform loads
    }
    unsigned int* __restrict__ dst = isx ? hx2 : hy2;
#pragma unroll
    for (int r = 0; r < 8; ++r) {
      const float o = __shfl_xor(acc[r], 1, 64);
      if (!(t & 1)) dst[(i0 + r) * 128 + (t >> 1)] = pack_f16x2(acc[r], o);
    }
  } else {
    const int n = b - 128;
    const float wv = W2[t * 256 + n];
    const float o = __shfl_xor(wv, 1, 64);
    if (!(t & 1)) W2T2[n * 128 + (t >> 1)] = pack_f16x2(wv, o);
  }
}

// ---------------------------------------------------------------------------
// Main fused kernel, v13: lean waves for 3 blocks/CU pipe overlap.
// Block = 256 thr (4 waves = 2 rh x 2 nq), grid = 1024 (ig 0..63 x jt 0..7 x
// nh 0..1). Wave: rows rh*32..+31 (mf=2), cols nh*128+nq*64..+63 (nf=4), full
// K=256. N is SPLIT across the two nh blocks (relu needs full K only; n-sum
// is linear after relu): nh=0 writes partial to out, nh=1 to part1; k_fin
// adds them + b3.
//   bq[8][4] half8 = 128 regs persistent B; acc[2][4] = 32 (init = b2).
// Per g (NO barriers, R12 structure): 8 kk x { 1 bcast hx b128 + 2 hy b128
//   (264-pad: balanced banks) + 2 relu8 + 8 MFMA f16 }, then epilogue:
//   pr = sum_nf fmax(acc,0)*w3, 4x DPP ror, select tree (validated R8),
//   red[(g*2+nq)*68+row64] (disjoint -> no sync).
// Barriers: 1 after staging, 1 before the partial write-out.
// MFMA f16 frag layout (verified R1/R7+):
//   A: row=l15, k=8*l4+e ; B: col=l15, k=8*l4+e ; C: col=l15, row=4*l4+reg
// ---------------------------------------------------------------------------
__launch_bounds__(256, 3)
__global__ void k_main(const unsigned int* __restrict__ hx2,
                       const unsigned int* __restrict__ hy2,
                       const unsigned int* __restrict__ W2T2,
                       const float* __restrict__ b2, const float* __restrict__ W3,
                       float* __restrict__ part0, float* __restrict__ part1) {
  __shared__ __attribute__((aligned(16))) _Float16 hyR[64 * 264];  // 33792 B
  __shared__ __attribute__((aligned(16))) unsigned int hxL[8 * 128];  // 4096 B
  __shared__ float red[16 * 68];                                   // 4352 B

  const int tid = threadIdx.x;
  const int lane = tid & 63;
  const int w = tid >> 6;        // wave 0..3
  const int l15 = lane & 15;
  const int l4 = lane >> 4;
  const int rh = w >> 1;         // rows rh*32..+31
  const int nq = w & 1;          // col sub-slice nq*64
  const int b = blockIdx.x;
  const int ig = b >> 4;
  const int jt = (b >> 1) & 7;
  const int nh = b & 1;          // N-half
  const int j0 = jt * 64;
  const int i0 = ig * 8;
  const int nbase = nh * 128 + nq * 64;

  // ---- stage hxL: 1024 uints / 256 thr = uint4 each ----
  *reinterpret_cast<uint4*>(&hxL[tid * 4]) =
      *reinterpret_cast<const uint4*>(&hx2[i0 * 128 + tid * 4]);

  // ---- stage hyR rows j0..j0+63 (wave w -> rows w*16..+15, R12 pattern) ----
  {
    const int rpar = lane >> 5;
    const int c32 = lane & 31;
    const unsigned int* __restrict__ hyb = hy2 + (j0 + w * 16 + rpar) * 128 + c32 * 4;
    _Float16* __restrict__ dst = &hyR[(w * 16 + rpar) * 264 + c32 * 8];
#pragma unroll
    for (int c = 0; c < 8; ++c) {
      const half8 hv = *reinterpret_cast<const half8*>(hyb + c * 256);
      *reinterpret_cast<half8*>(&dst[c * 2 * 264]) = hv;
    }
  }

  // ---- persistent B frags: col = nbase+nf*16+l15, k = kk*32+l4*8 ----
  half8 bq[8][4];
  {
    const unsigned int* bb = W2T2 + (nbase + l15) * 128 + l4 * 4;
#pragma unroll
    for (int nf = 0; nf < 4; ++nf)
#pragma unroll
      for (int kk = 0; kk < 8; ++kk)
        bq[kk][nf] = *reinterpret_cast<const half8*>(bb + nf * 2048 + kk * 16);
  }

  // ---- epilogue constants (b2 folded into acc init) ----
  float b2v[4], w3v[4];
#pragma unroll
  for (int nf = 0; nf < 4; ++nf) {
    b2v[nf] = b2[nbase + nf * 16 + l15];
    w3v[nf] = W3[nbase + nf * 16 + l15];
  }

  __syncthreads();  // hyR + hxL ready; g-loop barrier-free

  const _Float16* __restrict__ hyr = &hyR[(rh * 32 + l15) * 264 + l4 * 8];
  const _Float16* __restrict__ hxf = reinterpret_cast<const _Float16*>(hxL) + l4 * 8;

#pragma unroll 1
  for (int g = 0; g < 8; ++g) {
    f32x4 acc[2][4];
#pragma unroll
    for (int mf = 0; mf < 2; ++mf)
#pragma unroll
      for (int nf = 0; nf < 4; ++nf)
        acc[mf][nf] = (f32x4){b2v[nf], b2v[nf], b2v[nf], b2v[nf]};

    const _Float16* __restrict__ hxg = hxf + g * 256;
#pragma unroll
    for (int kk = 0; kk < 8; ++kk) {
      const half8 hx8 = *reinterpret_cast<const half8*>(hxg + kk * 32);
      const half8 af0 = relu8(*reinterpret_cast<const half8*>(hyr + kk * 32) + hx8);
      const half8 af1 = relu8(*reinterpret_cast<const half8*>(hyr + 16 * 264 + kk * 32) + hx8);
      __builtin_amdgcn_s_setprio(1);
#pragma unroll
      for (int nf = 0; nf < 4; ++nf)
        acc[0][nf] = __builtin_amdgcn_mfma_f32_16x16x32_f16(af0, bq[kk][nf], acc[0][nf], 0, 0, 0);
#pragma unroll
      for (int nf = 0; nf < 4; ++nf)
        acc[1][nf] = __builtin_amdgcn_mfma_f32_16x16x32_f16(af1, bq[kk][nf], acc[1][nf], 0, 0, 0);
      __builtin_amdgcn_s_setprio(0);
    }

    // ---- epilogue: pr = sum_nf fmax(acc,0)*w3 (b2 already in acc) ----
    float pr[2][4];
#pragma unroll
    for (int mf = 0; mf < 2; ++mf)
#pragma unroll
      for (int reg = 0; reg < 4; ++reg) {
        float p = fmaxf(acc[mf][0][reg], 0.f) * w3v[0] +
                  fmaxf(acc[mf][1][reg], 0.f) * w3v[1] +
                  fmaxf(acc[mf][2][reg], 0.f) * w3v[2] +
                  fmaxf(acc[mf][3][reg], 0.f) * w3v[3];
        p = dpp_ror_add<0x121>(p);
        p = dpp_ror_add<0x122>(p);
        p = dpp_ror_add<0x124>(p);
        p = dpp_ror_add<0x128>(p);
        pr[mf][reg] = p;
      }
    // select tree (validated R8): lane -> pr[l15>>3][(l15>>1)&3], 2-lane dup
    {
      const float a0 = (l15 & 2) ? pr[0][1] : pr[0][0];
      const float a1 = (l15 & 2) ? pr[0][3] : pr[0][2];
      const float a2 = (l15 & 2) ? pr[1][1] : pr[1][0];
      const float a3 = (l15 & 2) ? pr[1][3] : pr[1][2];
      const float c0 = (l15 & 4) ? a1 : a0;
      const float c1 = (l15 & 4) ? a3 : a2;
      const float v = (l15 & 8) ? c1 : c0;
      const int row64 = rh * 32 + (l15 >> 3) * 16 + l4 * 4 + ((l15 >> 1) & 3);
      red[(g * 2 + nq) * 68 + row64] = v;  // per-(g,nq) disjoint
    }
  }

  __syncthreads();  // all red written

  // ---- partial write-out: 512 vals / 256 thr, coalesced ----
  float* __restrict__ dst = nh ? part1 : part0;
#pragma unroll
  for (int rep = 0; rep < 2; ++rep) {
    const int idx = rep * 256 + tid;
    const int g = idx >> 6;
    const int row = idx & 63;
    dst[(i0 + g) * 512 + j0 + row] =
        red[(g * 2 + 0) * 68 + row] + red[(g * 2 + 1) * 68 + row];
  }
}

// out = out(part0) + part1 + b3
__global__ void k_fin(float* __restrict__ out, const float* __restrict__ part1,
                      const float* __restrict__ b3) {
  const int idx = blockIdx.x * 1024 + threadIdx.x;
  out[idx] = out[idx] + part1[idx] + b3[0];
}

extern "C" void kernel_launch(void* const* d_in, const int* in_sizes, int n_in,
                              void* d_out, int out_size, void* d_ws, size_t ws_size,
                              hipStream_t stream) {
  const float* x  = (const float*)d_in[0];
  const float* y  = (const float*)d_in[1];
  const float* W1 = (const float*)d_in[2];
  const float* b1 = (const float*)d_in[3];
  const float* W2 = (const float*)d_in[4];
  const float* b2 = (const float*)d_in[5];
  const float* W3 = (const float*)d_in[6];
  const float* b3 = (const float*)d_in[7];
  float* out = (float*)d_out;

  char* ws = (char*)d_ws;
  unsigned int* hx2  = (unsigned int*)ws;              // 262144 B
  unsigned int* hy2  = (unsigned int*)(ws + 262144);   // 262144 B
  unsigned int* W2T2 = (unsigned int*)(ws + 524288);   // 131072 B
  float* part1       = (float*)(ws + 655360);          // 1048576 B

  k_pre<<<384, 256, 0, stream>>>(x, y, W1, b1, W2, hx2, hy2, W2T2);
  k_main<<<1024, 256, 0, stream>>>(hx2, hy2, W2T2, b2, W3, out, part1);
  k_fin<<<256, 1024, 0, stream>>>(out, part1, b3);
}